// Round 1
// baseline (179.413 us; speedup 1.0000x reference)
//
#include <hip/hip_runtime.h>
#include <math.h>

#define LLEN   2048
#define NFFT   4096
#define DMODEL 256
#define NSTATE 64
#define NBATCH 16
#define PI_F   3.14159265358979323846f

#define PADIDX(a) ((a) + ((a) >> 4))
#define LDSN  (NFFT + (NFFT >> 4))   // 4352 float2 = 34816 B (k_fused)
#define LDSN2 (LLEN + (LLEN >> 4))   // 2176 float2 (k_mix)
#define KSTRIDE 2056                 // per-channel stride for Hc (f2), f=0..2048 + pad

__device__ inline float frcp(float x) { return __builtin_amdgcn_rcpf(x); }

#define RADIX4(ar0,ai0,ar1,ai1,ar2,ai2,ar3,ai3,S) do {                      \
    float s0r=(ar0)+(ar2), s0i=(ai0)+(ai2);                                 \
    float s1r=(ar0)-(ar2), s1i=(ai0)-(ai2);                                 \
    float s2r=(ar1)+(ar3), s2i=(ai1)+(ai3);                                 \
    float s3r=(ar1)-(ar3), s3i=(ai1)-(ai3);                                 \
    (ar0)=s0r+s2r; (ai0)=s0i+s2i;                                           \
    (ar2)=s0r-s2r; (ai2)=s0i-s2i;                                           \
    (ar1)=s1r-(S)*s3i; (ai1)=s1i+(S)*s3r;                                   \
    (ar3)=s1r+(S)*s3i; (ai3)=s1i-(S)*s3r;                                   \
} while (0)

// 16-point DFT in registers. Output X[u] (u = k0 + 4*k2) lands in slot 4*k0 + k2.
template<int SIGN>
__device__ inline void dft16(float xr[16], float xi[16]) {
    const float S = (float)SIGN;
    const float C1 = 0.9238795325112867f, S1 = 0.3826834323650898f;
    const float C2 = 0.7071067811865476f;
    RADIX4(xr[0],xi[0], xr[4],xi[4], xr[8],xi[8],  xr[12],xi[12], S);
    RADIX4(xr[1],xi[1], xr[5],xi[5], xr[9],xi[9],  xr[13],xi[13], S);
    RADIX4(xr[2],xi[2], xr[6],xi[6], xr[10],xi[10],xr[14],xi[14], S);
    RADIX4(xr[3],xi[3], xr[7],xi[7], xr[11],xi[11],xr[15],xi[15], S);
#define TW(idx, wr_, wi_) { float tr = xr[idx]*(wr_) - xi[idx]*(wi_);       \
    xi[idx] = xr[idx]*(wi_) + xi[idx]*(wr_); xr[idx] = tr; }
    TW(5,  C1,  S*S1);
    TW(6,  C2,  S*C2);
    TW(7,  S1,  S*C1);
    TW(9,  C2,  S*C2);
    TW(10, 0.f, S);
    TW(11, -C2, S*C2);
    TW(13, S1,  S*C1);
    TW(14, -C2, S*C2);
    TW(15, -C1, -S*S1);
#undef TW
    RADIX4(xr[0],xi[0],  xr[1],xi[1],  xr[2],xi[2],  xr[3],xi[3],  S);
    RADIX4(xr[4],xi[4],  xr[5],xi[5],  xr[6],xi[6],  xr[7],xi[7],  S);
    RADIX4(xr[8],xi[8],  xr[9],xi[9],  xr[10],xi[10],xr[11],xi[11],S);
    RADIX4(xr[12],xi[12],xr[13],xi[13],xr[14],xi[14],xr[15],xi[15],S);
}

template<int SIGN>
__device__ inline void dft8(float xr[8], float xi[8]) {
    const float S = (float)SIGN;
    const float C2 = 0.7071067811865476f;
    RADIX4(xr[0],xi[0], xr[2],xi[2], xr[4],xi[4], xr[6],xi[6], S);
    RADIX4(xr[1],xi[1], xr[3],xi[3], xr[5],xi[5], xr[7],xi[7], S);
    { float tr = xr[3]*C2 - xi[3]*(S*C2); xi[3] = xr[3]*(S*C2) + xi[3]*C2; xr[3] = tr; }
    { float tr = -S*xi[5]; xi[5] = S*xr[5]; xr[5] = tr; }
    { float tr = xr[7]*(-C2) - xi[7]*(S*C2); xi[7] = xr[7]*(S*C2) + xi[7]*(-C2); xr[7] = tr; }
    float br[8], bi[8];
#pragma unroll
    for (int k = 0; k < 4; ++k) {
        br[k]   = xr[2*k] + xr[2*k+1]; bi[k]   = xi[2*k] + xi[2*k+1];
        br[k+4] = xr[2*k] - xr[2*k+1]; bi[k+4] = xi[2*k] - xi[2*k+1];
    }
#pragma unroll
    for (int k = 0; k < 8; ++k) { xr[k] = br[k]; xi[k] = bi[k]; }
}

template<int SIGN>
__device__ inline void tw_apply16(float xr[16], float xi[16], float ang) {
    float wr[16], wi[16];
    __sincosf(ang, &wi[1], &wr[1]);
#pragma unroll
    for (int k = 1; k < 8; ++k) {
        wr[2*k]   = wr[k]*wr[k] - wi[k]*wi[k];
        wi[2*k]   = 2.f * wr[k] * wi[k];
        wr[2*k+1] = wr[k]*wr[k+1] - wi[k]*wi[k+1];
        wi[2*k+1] = wr[k]*wi[k+1] + wi[k]*wr[k+1];
    }
#pragma unroll
    for (int t = 1; t < 16; ++t) {
        float tr = xr[t]*wr[t] - xi[t]*wi[t];
        xi[t] = xr[t]*wi[t] + xi[t]*wr[t];
        xr[t] = tr;
    }
}

// one radix-16 Stockham stage. M = read stride, L = current sub-FFT len.
// PRUNE valid only for the final L=256 stage of a 4096 FFT: keep a<2048.
template<int SIGN, int M, int L, bool PRUNE>
__device__ inline void stage16(float2* X, int j, bool active) {
    float xr[16], xi[16];
    const int p = j & (L - 1);
    if (active) {
#pragma unroll
        for (int t = 0; t < 16; ++t) {
            float2 v = X[PADIDX(j + t * M)];
            xr[t] = v.x; xi[t] = v.y;
        }
        tw_apply16<SIGN>(xr, xi, ((float)SIGN * 2.f * PI_F / (float)(16 * L)) * (float)p);
        dft16<SIGN>(xr, xi);
    }
    __syncthreads();
    if (active) {
        const int base = 16 * j - 15 * p;
#pragma unroll
        for (int k0 = 0; k0 < 4; ++k0)
#pragma unroll
            for (int k2 = 0; k2 < 4; ++k2) {
                const int u = k0 + 4 * k2;
                if (!PRUNE || u < 8) {
                    const int a = base + u * L;
                    X[PADIDX(a)] = make_float2(xr[4*k0+k2], xi[4*k0+k2]);
                }
            }
    }
    __syncthreads();
}

// 4096-pt FFT, 256 threads, 16/thread. ZHI: input zero for idx>=2048 (skip reads).
// PRUNE: only outputs idx<2048 needed (skip half of final-stage stores).
template<int SIGN, bool ZHI, bool PRUNE>
__device__ inline void fft4096_f2(float2* X, int tid) {
    float xr[16], xi[16];
#pragma unroll
    for (int t = 0; t < 16; ++t) {
        if (ZHI && t >= 8) { xr[t] = 0.f; xi[t] = 0.f; }
        else { float2 v = X[PADIDX(tid + t * 256)]; xr[t] = v.x; xi[t] = v.y; }
    }
    dft16<SIGN>(xr, xi);
    __syncthreads();
#pragma unroll
    for (int k0 = 0; k0 < 4; ++k0)
#pragma unroll
        for (int k2 = 0; k2 < 4; ++k2)
            X[PADIDX(16 * tid + k0 + 4 * k2)] = make_float2(xr[4*k0+k2], xi[4*k0+k2]);
    __syncthreads();
    stage16<SIGN, 256, 16,  false>(X, tid, true);
    stage16<SIGN, 256, 256, PRUNE>(X, tid, true);
}

// 2048-pt FFT, radices [8,16,16]
template<int SIGN>
__device__ inline void fft2048_f2(float2* X, int tid) {
    float xr[8], xi[8];
#pragma unroll
    for (int t = 0; t < 8; ++t) {
        float2 v = X[PADIDX(tid + t * 256)];
        xr[t] = v.x; xi[t] = v.y;
    }
    dft8<SIGN>(xr, xi);
    __syncthreads();
#pragma unroll
    for (int u = 0; u < 8; ++u)
        X[PADIDX(8 * tid + u)] = make_float2(xr[u], xi[u]);
    __syncthreads();
    stage16<SIGN, 128, 8,   false>(X, tid, tid < 128);
    stage16<SIGN, 128, 128, false>(X, tid, tid < 128);
}

// ---- K_ar: at_roots, one l per thread (2048 blocks) --------------------------
__global__ __launch_bounds__(256) void k_ar(const float* __restrict__ p_ri,
                                            const float* __restrict__ lambda_ri,
                                            const float* __restrict__ B_ri,
                                            const float* __restrict__ Ct_ri,
                                            const float* __restrict__ log_step,
                                            float2* __restrict__ ar_out) {
    __shared__ float4 c0[NSTATE], c1[NSTATE];
    __shared__ float2 lam[NSTATE];
    const int d = blockIdx.x >> 3;
    const int l = ((blockIdx.x & 7) << 8) | threadIdx.x;
    const int tid = threadIdx.x;
    if (tid < NSTATE) {
        const int n = tid;
        const float px = p_ri[2*n], py = p_ri[2*n+1];
        lam[n] = make_float2(lambda_ri[2*n], lambda_ri[2*n+1]);
        const float Bx = B_ri[(d*NSTATE+n)*2], By = B_ri[(d*NSTATE+n)*2+1];
        const float Cx = Ct_ri[(d*NSTATE+n)*2], Cy = Ct_ri[(d*NSTATE+n)*2+1];
        c0[n] = make_float4(Cx*Bx + Cy*By, Cx*By - Cy*Bx,
                            Cx*px + Cy*py, Cx*py - Cy*px);
        c1[n] = make_float4(px*Bx + py*By, px*By - py*Bx, px*px + py*py, 0.f);
    }
    __syncthreads();

    const float tos = 2.f * __expf(-log_step[d]);
    float sn, cs;
    sincosf(2.f * PI_F * (float)l / (float)LLEN, &sn, &cs);
    const float opx = 1.f + cs, opy = sn;
    const float omx = 1.f - cs, omy = -sn;
    const float inv_op = frcp(opx*opx + opy*opy);
    const float gx = tos * (omx*opx + omy*opy) * inv_op;
    const float gy = tos * (omy*opx - omx*opy) * inv_op;
    const float ccx = 2.f * opx * inv_op, ccy = -2.f * opy * inv_op;

    float k00x = 0, k00y = 0, k01x = 0, k01y = 0;
    float k10x = 0, k10y = 0, k11x = 0, k11y = 0;
    for (int n = 0; n < NSTATE; ++n) {
        const float2 lm = lam[n];
        const float dx = gx - lm.x, dy = gy - lm.y;
        const float idn = frcp(dx*dx + dy*dy);
        const float ix = dx * idn, iy = -dy * idn;
        const float4 a = c0[n];
        const float4 b = c1[n];
        k00x += a.x*ix - a.y*iy;  k00y += a.x*iy + a.y*ix;
        k01x += a.z*ix - a.w*iy;  k01y += a.z*iy + a.w*ix;
        k10x += b.x*ix - b.y*iy;  k10y += b.x*iy + b.y*ix;
        k11x += b.z*ix;           k11y += b.z*iy;
    }
    const float nx = k01x*k10x - k01y*k10y;
    const float ny = k01x*k10y + k01y*k10x;
    const float dpx = 1.f + k11x, dpy = k11y;
    const float idq = frcp(dpx*dpx + dpy*dpy);
    const float qx = (nx*dpx + ny*dpy) * idq;
    const float qy = (ny*dpx - nx*dpy) * idq;
    const float rx = k00x - qx, ry = k00y - qy;
    ar_out[(size_t)d * LLEN + l] = make_float2(ccx*rx - ccy*ry, ccx*ry + ccy*rx);
}

// ---- K_mix: Khat from a (2x FFT2048 via even/odd identity), 256 blocks -------
__global__ __launch_bounds__(256, 4) void k_mix(const float2* __restrict__ a_in,
                                                float2* __restrict__ Hc) {
    __shared__ float2 X[LDSN2];
    const int tid = threadIdx.x;
    const int d = blockIdx.x;
    const float isc = 1.f / (float)NFFT;
    const float4* a4 = (const float4*)(a_in + (size_t)d * LLEN);
#pragma unroll
    for (int k = 0; k < 4; ++k) {
        const int v = tid + k * 256;
        const float4 w = a4[v];
        X[PADIDX(2 * v)]     = make_float2(w.x, w.y);
        X[PADIDX(2 * v + 1)] = make_float2(w.z, w.w);
    }
    __syncthreads();

    float2* H = Hc + (size_t)d * KSTRIDE;
    // even frequencies: Khat_{2m} = (a_{(-m) mod L} + conj(a_m)) / 2
    for (int m = tid; m <= 1024; m += 256) {
        const float2 am = X[PADIDX(m)];
        const float2 an = X[PADIDX((LLEN - m) & (LLEN - 1))];
        H[2 * m] = make_float2((an.x + am.x) * 0.5f * isc,
                               (an.y - am.y) * 0.5f * isc);
    }
    fft2048_f2<-1>(X, tid);     // A = F(a)

    // K_j = Re(A_j)/L ; modulate by e^{-2*pi*i*j/4096} (angle = -pi*j/2048)
#pragma unroll
    for (int k = 0; k < 8; ++k) {
        const int j = tid + k * 256;
        const int q = PADIDX(j);
        const float Kj = X[q].x * (1.f / (float)LLEN);
        float snj, csj;
        __sincosf(-PI_F * (float)j * (1.f / 2048.f), &snj, &csj);
        X[q] = make_float2(Kj * csj, Kj * snj);
    }
    __syncthreads();
    fft2048_f2<-1>(X, tid);     // W_m = Khat_{2m+1}

    for (int m = tid; m < 1024; m += 256) {
        const float2 w = X[PADIDX(m)];
        H[2 * m + 1] = make_float2(w.x * isc, w.y * isc);
    }
}

// ---- K_fused: per (batch, channel-pair). Packs z[t] = u[b,t,2c] + i*u[b,t,2c+1]
//      directly from native (B,L,D) layout (8B contiguous loads, 1KB stride).
//      Hermitian split -> per-channel H multiply -> recombine -> inverse FFT.
//      Skip connection fused (u kept in registers). Writes out in native layout.
//      XCD swizzle: XCD (i&7) owns channels [32x,32x+32) for all batches, slots
//      b-major so the 8 blocks sharing a 64B u/out line are dispatch-adjacent.
__global__ __launch_bounds__(256, 4) void k_fused(const float* __restrict__ u,
                                                  const float2* __restrict__ Hc,
                                                  const float* __restrict__ Dp,
                                                  float* __restrict__ out) {
    __shared__ float2 X[LDSN];
    const int i = blockIdx.x;           // 0..2047
    const int x = i & 7;                // xcd (heuristic: dispatch round-robins)
    const int s = i >> 3;               // slot within xcd, 0..255
    const int b  = s >> 4;              // 0..15
    const int cp = (x << 4) | (s & 15); // 0..127
    const int ch = cp * 2;
    const int tid = threadIdx.x;

    const float* ub = u + (size_t)b * (LLEN * DMODEL) + ch;
    float2 uv[8];
#pragma unroll
    for (int k = 0; k < 8; ++k) {
        const int t = tid + k * 256;
        uv[k] = *(const float2*)(ub + (size_t)t * DMODEL);
        X[PADIDX(t)] = uv[k];
    }
    __syncthreads();
    fft4096_f2<-1, true, false>(X, tid);

    const float2* Ha = Hc + (size_t)ch * KSTRIDE;
    const float2* Hb = Ha + KSTRIDE;
    for (int f = tid; f <= NFFT / 2; f += 256) {
        const int fb = (NFFT - f) & (NFFT - 1);
        const float2 Za = X[PADIDX(f)], Zb = X[PADIDX(fb)];
        // spectra of the two real channel signals
        const float xax = 0.5f * (Za.x + Zb.x), xay = 0.5f * (Za.y - Zb.y);
        const float xbx = 0.5f * (Za.y + Zb.y), xby = -0.5f * (Za.x - Zb.x);
        const float2 A = Ha[f], B = Hb[f];
        const float yax = xax*A.x - xay*A.y, yay = xax*A.y + xay*A.x;
        const float ybx = xbx*B.x - xby*B.y, yby = xbx*B.y + xby*B.x;
        // W[f] = Ya + i*Yb ; W[N-f] = conj(Ya) + i*conj(Yb) (both y real)
        X[PADIDX(f)] = make_float2(yax - yby, yay + ybx);
        if (fb != f)
            X[PADIDX(fb)] = make_float2(yax + yby, ybx - yay);
    }
    __syncthreads();
    fft4096_f2<+1, false, true>(X, tid);   // pruned: only t<2048 stored

    const float2 dp = *(const float2*)(Dp + ch);
    float* ob = out + (size_t)b * (LLEN * DMODEL) + ch;
#pragma unroll
    for (int k = 0; k < 8; ++k) {
        const int t = tid + k * 256;
        const float2 v = X[PADIDX(t)];
        *(float2*)(ob + (size_t)t * DMODEL) =
            make_float2(v.x + dp.x * uv[k].x, v.y + dp.y * uv[k].y);
    }
}

extern "C" void kernel_launch(void* const* d_in, const int* in_sizes, int n_in,
                              void* d_out, int out_size, void* d_ws, size_t ws_size,
                              hipStream_t stream) {
    const float* u         = (const float*)d_in[0];
    const float* p_ri      = (const float*)d_in[1];
    const float* lambda_ri = (const float*)d_in[2];
    const float* B_ri      = (const float*)d_in[3];
    const float* Ct_ri     = (const float*)d_in[4];
    const float* Dp        = (const float*)d_in[5];
    const float* log_step  = (const float*)d_in[6];
    float* out = (float*)d_out;

    // ws layout: Hc (256*2056 f2 = 4.21 MB) | a (256*2048 f2 = 4 MB)
    float2* Hc = (float2*)d_ws;
    float2* a  = (float2*)((char*)d_ws + (size_t)DMODEL * KSTRIDE * sizeof(float2));

    k_ar   <<<DMODEL * 8, 256, 0, stream>>>(p_ri, lambda_ri, B_ri, Ct_ri, log_step, a);
    k_mix  <<<DMODEL, 256, 0, stream>>>(a, Hc);
    k_fused<<<NBATCH * (DMODEL / 2), 256, 0, stream>>>(u, Hc, Dp, out);
}